// Round 5
// baseline (612.995 us; speedup 1.0000x reference)
//
#include <hip/hip_runtime.h>
#include <hip/hip_bf16.h>

#define HH    128
#define NHEAD 8
#define HDIM  16
#define EDIM  32
#define FFDIM 512

// float atomic max via int/uint monotone trick (valid with init = -large)
__device__ __forceinline__ void atomicMaxF(float* addr, float val) {
    if (val >= 0.0f) atomicMax((int*)addr, __float_as_int(val));
    else             atomicMin((unsigned int*)addr, __float_as_uint(val));
}

// ---------------------------------------------------------------------------
// K1: q,k,v projections (one block of 384 threads per node) + ws init
// ---------------------------------------------------------------------------
__global__ __launch_bounds__(384)
void qkv_kernel(const float* __restrict__ x,
                const float* __restrict__ Wq, const float* __restrict__ bq,
                const float* __restrict__ Wk, const float* __restrict__ bk,
                const float* __restrict__ Wv, const float* __restrict__ bv,
                float* __restrict__ q, float* __restrict__ k, float* __restrict__ v,
                float* __restrict__ mx, float* __restrict__ den, float* __restrict__ agg)
{
    const int row = blockIdx.x;
    const int tid = threadIdx.x;
    __shared__ float xs[HH];
    if (tid < HH) {
        xs[tid] = x[(size_t)row * HH + tid];
        agg[(size_t)row * HH + tid] = 0.0f;           // zero-init (ws is poisoned)
    } else if (tid < HH + NHEAD) {
        mx[row * NHEAD + (tid - HH)] = -3.4e38f;      // -inf for segment max
    } else if (tid < HH + 2 * NHEAD) {
        den[row * NHEAD + (tid - HH - NHEAD)] = 0.0f;
    }
    __syncthreads();
    const int which = tid >> 7;     // 0=q, 1=k, 2=v
    const int col   = tid & 127;
    const float* W = (which == 0) ? Wq : (which == 1) ? Wk : Wv;
    const float* b = (which == 0) ? bq : (which == 1) ? bk : bv;
    float acc = 0.0f;
    #pragma unroll 8
    for (int i = 0; i < HH; ++i) acc += xs[i] * W[i * HH + col];
    acc += b[col];
    float* outp = (which == 0) ? q : (which == 1) ? k : v;
    outp[(size_t)row * HH + col] = acc;
}

// ---------------------------------------------------------------------------
// K2: per-(edge,head) attention score + edge bias; atomicMax into mx[dst]
// ---------------------------------------------------------------------------
__global__ void score_kernel(const int* __restrict__ ei, int E,
                             const float* __restrict__ ea,
                             const float* __restrict__ We, const float* __restrict__ be,
                             const float* __restrict__ q, const float* __restrict__ k,
                             float* __restrict__ scores, float* __restrict__ mx)
{
    int idx = blockIdx.x * blockDim.x + threadIdx.x;
    if (idx >= E * NHEAD) return;
    int e = idx >> 3, h = idx & 7;
    int src = ei[e], dst = ei[E + e];
    const float* qp = q + (size_t)src * HH + h * HDIM;
    const float* kp = k + (size_t)dst * HH + h * HDIM;
    float s = 0.0f;
    #pragma unroll
    for (int d = 0; d < HDIM; ++d) s += qp[d] * kp[d];
    s *= 0.25f;                                        // 1/sqrt(16)
    float eb = be[h];
    const float* eap = ea + (size_t)e * EDIM;
    #pragma unroll
    for (int j = 0; j < EDIM; ++j) eb += eap[j] * We[j * NHEAD + h];
    s += eb;
    scores[idx] = s;
    atomicMaxF(&mx[dst * NHEAD + h], s);
}

// ---------------------------------------------------------------------------
// K3: ex = exp(score - mx[dst]);  den[dst] += ex   (in-place into scores)
// ---------------------------------------------------------------------------
__global__ void exp_kernel(const int* __restrict__ ei, int E,
                           float* __restrict__ scores,
                           const float* __restrict__ mx, float* __restrict__ den)
{
    int idx = blockIdx.x * blockDim.x + threadIdx.x;
    if (idx >= E * NHEAD) return;
    int e = idx >> 3, h = idx & 7;
    int dst = ei[E + e];
    float ex = expf(scores[idx] - mx[dst * NHEAD + h]);
    scores[idx] = ex;
    atomicAdd(&den[dst * NHEAD + h], ex);
}

// ---------------------------------------------------------------------------
// K4: agg[dst, f] += v[src, f] * ex/(den[dst]+1e-8)   (per edge-feature)
// ---------------------------------------------------------------------------
__global__ void agg_kernel(const int* __restrict__ ei, int E,
                           const float* __restrict__ ex, const float* __restrict__ den,
                           const float* __restrict__ v, float* __restrict__ agg)
{
    int idx = blockIdx.x * blockDim.x + threadIdx.x;
    if (idx >= E * HH) return;                         // 40.96M < 2^31
    int e = idx >> 7, f = idx & 127;
    int h = f >> 4;
    int src = ei[e], dst = ei[E + e];
    float a = ex[e * NHEAD + h] / (den[dst * NHEAD + h] + 1e-8f);
    atomicAdd(&agg[(size_t)dst * HH + f], v[(size_t)src * HH + f] * a);
}

// ---------------------------------------------------------------------------
// K5: out = agg @ Wo + bo;  x1 = LN(x + out)   (block of 128 per node)
// ---------------------------------------------------------------------------
__global__ __launch_bounds__(128)
void oproj_ln_kernel(const float* __restrict__ x, const float* __restrict__ agg,
                     const float* __restrict__ Wo, const float* __restrict__ bo,
                     const float* __restrict__ g, const float* __restrict__ bln,
                     float* __restrict__ x1)
{
    const int row = blockIdx.x, t = threadIdx.x;
    __shared__ float as[HH];
    __shared__ float red[2];
    as[t] = agg[(size_t)row * HH + t];
    __syncthreads();
    float acc = 0.0f;
    #pragma unroll 8
    for (int i = 0; i < HH; ++i) acc += as[i] * Wo[i * HH + t];
    float y = x[(size_t)row * HH + t] + acc + bo[t];

    // mean over 128 (2 waves)
    float s = y;
    #pragma unroll
    for (int o = 32; o > 0; o >>= 1) s += __shfl_down(s, o);
    if ((t & 63) == 0) red[t >> 6] = s;
    __syncthreads();
    float mean = (red[0] + red[1]) * (1.0f / HH);
    float d = y - mean;
    float s2 = d * d;
    __syncthreads();
    #pragma unroll
    for (int o = 32; o > 0; o >>= 1) s2 += __shfl_down(s2, o);
    if ((t & 63) == 0) red[t >> 6] = s2;
    __syncthreads();
    float var = (red[0] + red[1]) * (1.0f / HH);
    x1[(size_t)row * HH + t] = d * rsqrtf(var + 1e-5f) * g[t] + bln[t];
}

// ---------------------------------------------------------------------------
// K6: h = gelu(x1@W1+b1); out = LN(x1 + h@W2 + b2)  -> fp32  (block 512/node)
// ---------------------------------------------------------------------------
__global__ __launch_bounds__(512)
void ffn_ln_kernel(const float* __restrict__ x1,
                   const float* __restrict__ W1, const float* __restrict__ b1,
                   const float* __restrict__ W2, const float* __restrict__ b2,
                   const float* __restrict__ g, const float* __restrict__ bln,
                   float* __restrict__ out)
{
    const int row = blockIdx.x, t = threadIdx.x;
    __shared__ float xs[HH];
    __shared__ float hs[FFDIM];
    __shared__ float red[2];
    if (t < HH) xs[t] = x1[(size_t)row * HH + t];
    __syncthreads();
    float acc = b1[t];
    #pragma unroll 8
    for (int i = 0; i < HH; ++i) acc += xs[i] * W1[i * FFDIM + t];
    hs[t] = 0.5f * acc * (1.0f + erff(acc * 0.70710678118f));   // exact gelu
    __syncthreads();

    float y = 0.0f;
    if (t < HH) {
        float o = b2[t];
        #pragma unroll 8
        for (int j = 0; j < FFDIM; ++j) o += hs[j] * W2[j * HH + t];
        y = xs[t] + o;
    }
    // LN over first 128 threads; all 512 run the shuffles/barriers
    float s = (t < HH) ? y : 0.0f;
    #pragma unroll
    for (int o = 32; o > 0; o >>= 1) s += __shfl_down(s, o);
    __syncthreads();
    if ((t & 63) == 0 && t < HH) red[t >> 6] = s;
    __syncthreads();
    float mean = (red[0] + red[1]) * (1.0f / HH);
    float d = (t < HH) ? (y - mean) : 0.0f;
    float s2 = d * d;
    #pragma unroll
    for (int o = 32; o > 0; o >>= 1) s2 += __shfl_down(s2, o);
    __syncthreads();
    if ((t & 63) == 0 && t < HH) red[t >> 6] = s2;
    __syncthreads();
    float var = (red[0] + red[1]) * (1.0f / HH);
    if (t < HH)
        out[(size_t)row * HH + t] = d * rsqrtf(var + 1e-5f) * g[t] + bln[t];
}

// ---------------------------------------------------------------------------
extern "C" void kernel_launch(void* const* d_in, const int* in_sizes, int n_in,
                              void* d_out, int out_size, void* d_ws, size_t ws_size,
                              hipStream_t stream)
{
    const float* x   = (const float*)d_in[0];
    const int*   ei  = (const int*)d_in[1];
    const float* ea  = (const float*)d_in[2];
    const float* Wq  = (const float*)d_in[3];
    const float* bq  = (const float*)d_in[4];
    const float* Wk  = (const float*)d_in[5];
    const float* bk  = (const float*)d_in[6];
    const float* Wv  = (const float*)d_in[7];
    const float* bv  = (const float*)d_in[8];
    const float* We  = (const float*)d_in[9];
    const float* be  = (const float*)d_in[10];
    const float* Wo  = (const float*)d_in[11];
    const float* bo  = (const float*)d_in[12];
    const float* l1g = (const float*)d_in[13];
    const float* l1b = (const float*)d_in[14];
    const float* W1  = (const float*)d_in[15];
    const float* b1  = (const float*)d_in[16];
    const float* W2  = (const float*)d_in[17];
    const float* b2  = (const float*)d_in[18];
    const float* l2g = (const float*)d_in[19];
    const float* l2b = (const float*)d_in[20];
    float* out = (float*)d_out;

    const int n = in_sizes[0] / HH;       // 10000
    const int E = in_sizes[1] / 2;        // 320000

    float* ws  = (float*)d_ws;
    float* q   = ws;
    float* k   = q   + (size_t)n * HH;
    float* v   = k   + (size_t)n * HH;
    float* sc  = v   + (size_t)n * HH;    // scores, then ex (in-place)
    float* mx  = sc  + (size_t)E * NHEAD;
    float* den = mx  + (size_t)n * NHEAD;
    float* agg = den + (size_t)n * NHEAD;
    float* x1  = agg + (size_t)n * HH;

    qkv_kernel<<<n, 384, 0, stream>>>(x, Wq, bq, Wk, bk, Wv, bv,
                                      q, k, v, mx, den, agg);

    int eh = E * NHEAD;
    score_kernel<<<(eh + 255) / 256, 256, 0, stream>>>(ei, E, ea, We, be, q, k, sc, mx);
    exp_kernel<<<(eh + 255) / 256, 256, 0, stream>>>(ei, E, sc, mx, den);

    int ef = E * HH;
    agg_kernel<<<(ef + 255) / 256, 256, 0, stream>>>(ei, E, sc, den, v, agg);

    oproj_ln_kernel<<<n, 128, 0, stream>>>(x, agg, Wo, bo, l1g, l1b, x1);
    ffn_ln_kernel<<<n, 512, 0, stream>>>(x1, W1, b1, W2, b2, l2g, l2b, out);
}

// Round 7
// 448.996 us; speedup vs baseline: 1.3653x; 1.3653x over previous
//
#include <hip/hip_runtime.h>
#include <hip/hip_bf16.h>

#define HH    128
#define NHEAD 8
#define HDIM  16
#define EDIM  32
#define FFDIM 512
#define BM    16     // node rows per block for tiled GEMM kernels

// float atomic max via int/uint monotone trick (valid with init = -large)
__device__ __forceinline__ void atomicMaxF(float* addr, float val) {
    if (val >= 0.0f) atomicMax((int*)addr, __float_as_int(val));
    else             atomicMin((unsigned int*)addr, __float_as_uint(val));
}

// ---------------------------------------------------------------------------
// K1: q,k,v projections, tiled: BM=16 rows/block, 512 threads.
// thread t: rg=t>>7 (rows 4rg..4rg+3), c=t&127 (one col of each of q,k,v).
// Weights read ONCE per block (16x reuse) instead of once per row.
// Also inits mx/den/agg for this row tile (ws is poisoned each call).
// ---------------------------------------------------------------------------
__global__ __launch_bounds__(512)
void qkv_kernel(const float* __restrict__ x,
                const float* __restrict__ Wq, const float* __restrict__ bq,
                const float* __restrict__ Wk, const float* __restrict__ bk,
                const float* __restrict__ Wv, const float* __restrict__ bv,
                float* __restrict__ q, float* __restrict__ k, float* __restrict__ v,
                float* __restrict__ mx, float* __restrict__ den, float* __restrict__ agg)
{
    const int row0 = blockIdx.x * BM;
    const int t  = threadIdx.x;
    const int rg = t >> 7;
    const int c  = t & 127;
    __shared__ float xs[BM * HH];

    // init softmax state + agg for this tile
    if (t < BM * NHEAD)            mx[row0 * NHEAD + t] = -3.4e38f;
    else if (t < 2 * BM * NHEAD)   den[row0 * NHEAD + (t - BM * NHEAD)] = 0.0f;
    {
        float4 z = make_float4(0.f, 0.f, 0.f, 0.f);
        *(float4*)&agg[(size_t)row0 * HH + t * 4] = z;
        // stage x tile (16 rows x 128) — 4 floats per thread, coalesced
        *(float4*)&xs[t * 4] = *(const float4*)&x[(size_t)row0 * HH + t * 4];
    }
    __syncthreads();

    float aq[4] = {0.f, 0.f, 0.f, 0.f};
    float ak[4] = {0.f, 0.f, 0.f, 0.f};
    float av[4] = {0.f, 0.f, 0.f, 0.f};
    for (int i0 = 0; i0 < HH; i0 += 4) {
        float4 xr[4];
        #pragma unroll
        for (int r = 0; r < 4; ++r)
            xr[r] = *(const float4*)&xs[(4 * rg + r) * HH + i0];   // wave-broadcast
        #pragma unroll
        for (int u = 0; u < 4; ++u) {
            float wq = Wq[(i0 + u) * HH + c];
            float wk = Wk[(i0 + u) * HH + c];
            float wv = Wv[(i0 + u) * HH + c];
            #pragma unroll
            for (int r = 0; r < 4; ++r) {
                float xv = ((const float*)&xr[r])[u];
                aq[r] += xv * wq;  ak[r] += xv * wk;  av[r] += xv * wv;
            }
        }
    }
    float bqv = bq[c], bkv = bk[c], bvv = bv[c];
    #pragma unroll
    for (int r = 0; r < 4; ++r) {
        size_t o = (size_t)(row0 + 4 * rg + r) * HH + c;
        q[o] = aq[r] + bqv;
        k[o] = ak[r] + bkv;
        v[o] = av[r] + bvv;
    }
}

// ---------------------------------------------------------------------------
// K2: per-(edge,head) attention score + edge bias; atomicMax into mx[dst]
// ---------------------------------------------------------------------------
__global__ void score_kernel(const int* __restrict__ ei, int E,
                             const float* __restrict__ ea,
                             const float* __restrict__ We, const float* __restrict__ be,
                             const float* __restrict__ q, const float* __restrict__ k,
                             float* __restrict__ scores, float* __restrict__ mx)
{
    int idx = blockIdx.x * blockDim.x + threadIdx.x;
    if (idx >= E * NHEAD) return;
    int e = idx >> 3, h = idx & 7;
    int src = ei[e], dst = ei[E + e];
    const float* qp = q + (size_t)src * HH + h * HDIM;
    const float* kp = k + (size_t)dst * HH + h * HDIM;
    float s = 0.0f;
    #pragma unroll
    for (int d = 0; d < HDIM; ++d) s += qp[d] * kp[d];
    s *= 0.25f;                                        // 1/sqrt(16)
    float eb = be[h];
    const float* eap = ea + (size_t)e * EDIM;
    #pragma unroll
    for (int j = 0; j < EDIM; ++j) eb += eap[j] * We[j * NHEAD + h];
    s += eb;
    scores[idx] = s;
    atomicMaxF(&mx[dst * NHEAD + h], s);
}

// ---------------------------------------------------------------------------
// K3: ex = exp(score - mx[dst]);  den[dst] += ex   (in-place into scores)
// ---------------------------------------------------------------------------
__global__ void exp_kernel(const int* __restrict__ ei, int E,
                           float* __restrict__ scores,
                           const float* __restrict__ mx, float* __restrict__ den)
{
    int idx = blockIdx.x * blockDim.x + threadIdx.x;
    if (idx >= E * NHEAD) return;
    int e = idx >> 3, h = idx & 7;
    int dst = ei[E + e];
    float ex = expf(scores[idx] - mx[dst * NHEAD + h]);
    scores[idx] = ex;
    atomicAdd(&den[dst * NHEAD + h], ex);
}

// ---------------------------------------------------------------------------
// K4: agg[dst, f] += v[src, f] * ex/(den[dst]+1e-8)   (per edge-feature)
// ---------------------------------------------------------------------------
__global__ void agg_kernel(const int* __restrict__ ei, int E,
                           const float* __restrict__ ex, const float* __restrict__ den,
                           const float* __restrict__ v, float* __restrict__ agg)
{
    int idx = blockIdx.x * blockDim.x + threadIdx.x;
    if (idx >= E * HH) return;                         // 40.96M < 2^31
    int e = idx >> 7, f = idx & 127;
    int h = f >> 4;
    int src = ei[e], dst = ei[E + e];
    float a = ex[e * NHEAD + h] / (den[dst * NHEAD + h] + 1e-8f);
    atomicAdd(&agg[(size_t)dst * HH + f], v[(size_t)src * HH + f] * a);
}

// ---------------------------------------------------------------------------
// K5 (fused): out0 = agg@Wo+bo; x1 = LN1(x+out0);
//             h = gelu(x1@W1+b1); out = LN2(x1 + h@W2+b2)
// BM=16 rows/block, 512 threads. Weights read once per block (16x reuse).
// thread t: rg=t>>7, c=t&127. oproj/GEMM2: 4 rows x 1 col. GEMM1: 4 rows x
// cols 4c..4c+3. Row LN reduction across 128 threads (waves 2rg, 2rg+1).
// ---------------------------------------------------------------------------
__global__ __launch_bounds__(512)
void tail_kernel(const float* __restrict__ x, const float* __restrict__ agg,
                 const float* __restrict__ Wo, const float* __restrict__ bo,
                 const float* __restrict__ l1g, const float* __restrict__ l1b,
                 const float* __restrict__ W1, const float* __restrict__ b1,
                 const float* __restrict__ W2, const float* __restrict__ b2,
                 const float* __restrict__ l2g, const float* __restrict__ l2b,
                 float* __restrict__ out)
{
    const int row0 = blockIdx.x * BM;
    const int t  = threadIdx.x;
    const int rg = t >> 7;
    const int c  = t & 127;
    const int wavehalf = (t >> 6) & 1;

    __shared__ float xs[BM * HH];       // agg tile, then x1 tile
    __shared__ float hs[BM * FFDIM];    // gelu(h) tile
    __shared__ float redS[8][4], redS2[8][4];

    // stage agg tile
    *(float4*)&xs[t * 4] = *(const float4*)&agg[(size_t)row0 * HH + t * 4];
    __syncthreads();

    // ---- oproj: y[r] = (agg @ Wo)[row, c] ----
    float y[4] = {0.f, 0.f, 0.f, 0.f};
    for (int i0 = 0; i0 < HH; i0 += 4) {
        float4 ar[4];
        #pragma unroll
        for (int r = 0; r < 4; ++r)
            ar[r] = *(const float4*)&xs[(4 * rg + r) * HH + i0];
        #pragma unroll
        for (int u = 0; u < 4; ++u) {
            float w = Wo[(i0 + u) * HH + c];
            #pragma unroll
            for (int r = 0; r < 4; ++r) y[r] += ((const float*)&ar[r])[u] * w;
        }
    }
    {
        float bov = bo[c];
        #pragma unroll
        for (int r = 0; r < 4; ++r)
            y[r] += bov + x[(size_t)(row0 + 4 * rg + r) * HH + c];   // residual
    }

    // ---- LN1 (sum + sumsq one-pass) ----
    float s[4], s2[4];
    #pragma unroll
    for (int r = 0; r < 4; ++r) { s[r] = y[r]; s2[r] = y[r] * y[r]; }
    #pragma unroll
    for (int off = 32; off > 0; off >>= 1) {
        #pragma unroll
        for (int r = 0; r < 4; ++r) {
            s[r]  += __shfl_down(s[r],  off);
            s2[r] += __shfl_down(s2[r], off);
        }
    }
    if ((t & 63) == 0) {
        #pragma unroll
        for (int r = 0; r < 4; ++r) {
            redS [rg * 2 + wavehalf][r] = s[r];
            redS2[rg * 2 + wavehalf][r] = s2[r];
        }
    }
    __syncthreads();
    float x1v[4];
    {
        float g1 = l1g[c], bb1 = l1b[c];
        #pragma unroll
        for (int r = 0; r < 4; ++r) {
            float ssum = redS [rg * 2][r] + redS [rg * 2 + 1][r];
            float ssq  = redS2[rg * 2][r] + redS2[rg * 2 + 1][r];
            float mean = ssum * (1.0f / HH);
            float var  = ssq  * (1.0f / HH) - mean * mean;
            x1v[r] = (y[r] - mean) * rsqrtf(var + 1e-5f) * g1 + bb1;
        }
    }
    // overwrite xs with x1 (all xs reads completed before the barrier above)
    #pragma unroll
    for (int r = 0; r < 4; ++r) xs[(4 * rg + r) * HH + c] = x1v[r];
    __syncthreads();

    // ---- FFN GEMM1: h[r][cc], rows 4rg..+3, cols 4c..4c+3 ----
    float h[4][4];
    #pragma unroll
    for (int r = 0; r < 4; ++r)
        #pragma unroll
        for (int cc = 0; cc < 4; ++cc) h[r][cc] = 0.f;
    for (int i0 = 0; i0 < HH; i0 += 4) {
        float4 xr[4];
        #pragma unroll
        for (int r = 0; r < 4; ++r)
            xr[r] = *(const float4*)&xs[(4 * rg + r) * HH + i0];
        #pragma unroll
        for (int u = 0; u < 4; ++u) {
            float4 w = *(const float4*)&W1[(size_t)(i0 + u) * FFDIM + 4 * c];
            #pragma unroll
            for (int r = 0; r < 4; ++r) {
                float xv = ((const float*)&xr[r])[u];
                h[r][0] += xv * w.x;  h[r][1] += xv * w.y;
                h[r][2] += xv * w.z;  h[r][3] += xv * w.w;
            }
        }
    }
    {
        float4 b1v = *(const float4*)&b1[4 * c];
        #pragma unroll
        for (int r = 0; r < 4; ++r) {
            float4 hv;
            float a0 = h[r][0] + b1v.x, a1 = h[r][1] + b1v.y;
            float a2 = h[r][2] + b1v.z, a3 = h[r][3] + b1v.w;
            hv.x = 0.5f * a0 * (1.0f + erff(a0 * 0.70710678118f));
            hv.y = 0.5f * a1 * (1.0f + erff(a1 * 0.70710678118f));
            hv.z = 0.5f * a2 * (1.0f + erff(a2 * 0.70710678118f));
            hv.w = 0.5f * a3 * (1.0f + erff(a3 * 0.70710678118f));
            *(float4*)&hs[(4 * rg + r) * FFDIM + 4 * c] = hv;
        }
    }
    __syncthreads();

    // ---- FFN GEMM2: y2[r] = (hs @ W2)[row, c] ----
    float y2[4] = {0.f, 0.f, 0.f, 0.f};
    for (int j0 = 0; j0 < FFDIM; j0 += 4) {
        float4 hr[4];
        #pragma unroll
        for (int r = 0; r < 4; ++r)
            hr[r] = *(const float4*)&hs[(4 * rg + r) * FFDIM + j0];
        #pragma unroll
        for (int u = 0; u < 4; ++u) {
            float w = W2[(size_t)(j0 + u) * HH + c];
            #pragma unroll
            for (int r = 0; r < 4; ++r) y2[r] += ((const float*)&hr[r])[u] * w;
        }
    }
    {
        float b2v = b2[c];
        #pragma unroll
        for (int r = 0; r < 4; ++r) y2[r] += b2v + x1v[r];   // residual
    }

    // ---- LN2 ----
    #pragma unroll
    for (int r = 0; r < 4; ++r) { s[r] = y2[r]; s2[r] = y2[r] * y2[r]; }
    #pragma unroll
    for (int off = 32; off > 0; off >>= 1) {
        #pragma unroll
        for (int r = 0; r < 4; ++r) {
            s[r]  += __shfl_down(s[r],  off);
            s2[r] += __shfl_down(s2[r], off);
        }
    }
    if ((t & 63) == 0) {
        #pragma unroll
        for (int r = 0; r < 4; ++r) {
            redS [rg * 2 + wavehalf][r] = s[r];
            redS2[rg * 2 + wavehalf][r] = s2[r];
        }
    }
    __syncthreads();
    {
        float g2 = l2g[c], bb2 = l2b[c];
        #pragma unroll
        for (int r = 0; r < 4; ++r) {
            float ssum = redS [rg * 2][r] + redS [rg * 2 + 1][r];
            float ssq  = redS2[rg * 2][r] + redS2[rg * 2 + 1][r];
            float mean = ssum * (1.0f / HH);
            float var  = ssq  * (1.0f / HH) - mean * mean;
            out[(size_t)(row0 + 4 * rg + r) * HH + c] =
                (y2[r] - mean) * rsqrtf(var + 1e-5f) * g2 + bb2;
        }
    }
}

// ---------------------------------------------------------------------------
extern "C" void kernel_launch(void* const* d_in, const int* in_sizes, int n_in,
                              void* d_out, int out_size, void* d_ws, size_t ws_size,
                              hipStream_t stream)
{
    const float* x   = (const float*)d_in[0];
    const int*   ei  = (const int*)d_in[1];
    const float* ea  = (const float*)d_in[2];
    const float* Wq  = (const float*)d_in[3];
    const float* bq  = (const float*)d_in[4];
    const float* Wk  = (const float*)d_in[5];
    const float* bk  = (const float*)d_in[6];
    const float* Wv  = (const float*)d_in[7];
    const float* bv  = (const float*)d_in[8];
    const float* We  = (const float*)d_in[9];
    const float* be  = (const float*)d_in[10];
    const float* Wo  = (const float*)d_in[11];
    const float* bo  = (const float*)d_in[12];
    const float* l1g = (const float*)d_in[13];
    const float* l1b = (const float*)d_in[14];
    const float* W1  = (const float*)d_in[15];
    const float* b1  = (const float*)d_in[16];
    const float* W2  = (const float*)d_in[17];
    const float* b2  = (const float*)d_in[18];
    const float* l2g = (const float*)d_in[19];
    const float* l2b = (const float*)d_in[20];
    float* out = (float*)d_out;

    const int n = in_sizes[0] / HH;       // 10000
    const int E = in_sizes[1] / 2;        // 320000

    float* ws  = (float*)d_ws;
    float* q   = ws;
    float* k   = q   + (size_t)n * HH;
    float* v   = k   + (size_t)n * HH;
    float* sc  = v   + (size_t)n * HH;    // scores, then ex (in-place)
    float* mx  = sc  + (size_t)E * NHEAD;
    float* den = mx  + (size_t)n * NHEAD;
    float* agg = den + (size_t)n * NHEAD;

    qkv_kernel<<<n / BM, 512, 0, stream>>>(x, Wq, bq, Wk, bk, Wv, bv,
                                           q, k, v, mx, den, agg);

    int eh = E * NHEAD;
    score_kernel<<<(eh + 255) / 256, 256, 0, stream>>>(ei, E, ea, We, be, q, k, sc, mx);
    exp_kernel<<<(eh + 255) / 256, 256, 0, stream>>>(ei, E, sc, mx, den);

    int ef = E * HH;
    agg_kernel<<<(ef + 255) / 256, 256, 0, stream>>>(ei, E, sc, den, v, agg);

    tail_kernel<<<n / BM, 512, 0, stream>>>(x, agg, Wo, bo, l1g, l1b,
                                            W1, b1, W2, b2, l2g, l2b, out);
}

// Round 9
// 324.092 us; speedup vs baseline: 1.8914x; 1.3854x over previous
//
#include <hip/hip_runtime.h>
#include <hip/hip_bf16.h>

#define HH    128
#define NHEAD 8
#define HDIM  16
#define EDIM  32
#define FFDIM 512
#define BM    16     // node rows per block for tiled GEMM kernels
#define CHUNK 16     // edges per chunk in edge_kernel

// ---------------------------------------------------------------------------
// K1: q,k,v projections, tiled: BM=16 rows/block, 512 threads.
// Also zeroes cnt/cursor for the CSR build (ws is poisoned each call).
// ---------------------------------------------------------------------------
__global__ __launch_bounds__(512)
void qkv_kernel(const float* __restrict__ x,
                const float* __restrict__ Wq, const float* __restrict__ bq,
                const float* __restrict__ Wk, const float* __restrict__ bk,
                const float* __restrict__ Wv, const float* __restrict__ bv,
                float* __restrict__ q, float* __restrict__ k, float* __restrict__ v,
                int* __restrict__ cnt, int* __restrict__ cursor)
{
    const int row0 = blockIdx.x * BM;
    const int t  = threadIdx.x;
    const int rg = t >> 7;
    const int c  = t & 127;
    __shared__ float xs[BM * HH];

    if (t < BM)                cnt[row0 + t] = 0;
    else if (t < 2 * BM)       cursor[row0 + (t - BM)] = 0;
    // stage x tile (16 rows x 128) — 4 floats per thread, coalesced
    *(float4*)&xs[t * 4] = *(const float4*)&x[(size_t)row0 * HH + t * 4];
    __syncthreads();

    float aq[4] = {0.f, 0.f, 0.f, 0.f};
    float ak[4] = {0.f, 0.f, 0.f, 0.f};
    float av[4] = {0.f, 0.f, 0.f, 0.f};
    for (int i0 = 0; i0 < HH; i0 += 4) {
        float4 xr[4];
        #pragma unroll
        for (int r = 0; r < 4; ++r)
            xr[r] = *(const float4*)&xs[(4 * rg + r) * HH + i0];   // wave-broadcast
        #pragma unroll
        for (int u = 0; u < 4; ++u) {
            float wq = Wq[(i0 + u) * HH + c];
            float wk = Wk[(i0 + u) * HH + c];
            float wv = Wv[(i0 + u) * HH + c];
            #pragma unroll
            for (int r = 0; r < 4; ++r) {
                float xv = ((const float*)&xr[r])[u];
                aq[r] += xv * wq;  ak[r] += xv * wk;  av[r] += xv * wv;
            }
        }
    }
    float bqv = bq[c], bkv = bk[c], bvv = bv[c];
    #pragma unroll
    for (int r = 0; r < 4; ++r) {
        size_t o = (size_t)(row0 + 4 * rg + r) * HH + c;
        q[o] = aq[r] + bqv;
        k[o] = ak[r] + bkv;
        v[o] = av[r] + bvv;
    }
}

// ---------------------------------------------------------------------------
// K2: degree histogram over dst
// ---------------------------------------------------------------------------
__global__ void hist_kernel(const int* __restrict__ ei, int E, int* __restrict__ cnt)
{
    int e = blockIdx.x * 256 + threadIdx.x;
    if (e < E) atomicAdd(&cnt[ei[E + e]], 1);
}

// ---------------------------------------------------------------------------
// K3: exclusive prefix sum of cnt[0..n) -> rowptr[0..n]  (single block)
// ---------------------------------------------------------------------------
#define SCAN_T 1024
__global__ __launch_bounds__(SCAN_T)
void scan_kernel(const int* __restrict__ cnt, int n, int* __restrict__ rowptr)
{
    __shared__ int part[SCAN_T];
    const int t = threadIdx.x;
    const int per = (n + SCAN_T - 1) / SCAN_T;
    const int beg = t * per;
    const int end = min(beg + per, n);
    int sum = 0;
    for (int i = beg; i < end; ++i) sum += cnt[i];
    part[t] = sum;
    __syncthreads();
    // Hillis-Steele inclusive scan
    for (int off = 1; off < SCAN_T; off <<= 1) {
        int vv = (t >= off) ? part[t - off] : 0;
        __syncthreads();
        part[t] += vv;
        __syncthreads();
    }
    int base = (t == 0) ? 0 : part[t - 1];
    for (int i = beg; i < end; ++i) { rowptr[i] = base; base += cnt[i]; }
    if (t == SCAN_T - 1) rowptr[n] = base;
}

// ---------------------------------------------------------------------------
// K4: scatter edges into CSR slots; compute edge bias (ea@We+be) into
//     csr_eb (CSR-ordered so the edge kernel reads it contiguously).
// ---------------------------------------------------------------------------
__global__ __launch_bounds__(256)
void scatter_kernel(const int* __restrict__ ei, int E,
                    const float* __restrict__ ea,
                    const float* __restrict__ We, const float* __restrict__ be,
                    const int* __restrict__ rowptr, int* __restrict__ cursor,
                    int* __restrict__ csr_src, float* __restrict__ csr_eb)
{
    __shared__ float wsh[EDIM * NHEAD];
    __shared__ float bsh[NHEAD];
    const int t = threadIdx.x;
    if (t < EDIM * NHEAD) wsh[t] = We[t];
    if (t < NHEAD) bsh[t] = be[t];
    __syncthreads();
    int e = blockIdx.x * 256 + t;
    if (e >= E) return;
    int src = ei[e], dst = ei[E + e];
    int slot = rowptr[dst] + atomicAdd(&cursor[dst], 1);
    csr_src[slot] = src;
    float eb[NHEAD];
    #pragma unroll
    for (int h = 0; h < NHEAD; ++h) eb[h] = bsh[h];
    const float* eap = ea + (size_t)e * EDIM;
    #pragma unroll
    for (int j0 = 0; j0 < EDIM; j0 += 4) {
        float4 a = *(const float4*)&eap[j0];
        #pragma unroll
        for (int h = 0; h < NHEAD; ++h) {
            eb[h] += a.x * wsh[(j0    ) * NHEAD + h]
                   + a.y * wsh[(j0 + 1) * NHEAD + h]
                   + a.z * wsh[(j0 + 2) * NHEAD + h]
                   + a.w * wsh[(j0 + 3) * NHEAD + h];
        }
    }
    #pragma unroll
    for (int h = 0; h < NHEAD; ++h) csr_eb[(size_t)slot * NHEAD + h] = eb[h];
}

// ---------------------------------------------------------------------------
// K5: fused edge phase — per dst node: scores + online softmax + weighted
// aggregation. One block of 128 threads per node. No atomics.
// Phase A roles: c=t>>3 (edge in chunk), h=t&7 (head).
// Phase B roles: f=t (feature), fh=t>>4 (head of feature).
// ---------------------------------------------------------------------------
__global__ __launch_bounds__(128)
void edge_kernel(const float* __restrict__ q, const float* __restrict__ k,
                 const float* __restrict__ v,
                 const int* __restrict__ rowptr,
                 const int* __restrict__ csr_src, const float* __restrict__ csr_eb,
                 float* __restrict__ agg)
{
    const int node = blockIdx.x;
    const int t = threadIdx.x;
    const int c = t >> 3, h = t & 7;
    const int f = t, fh = t >> 4;
    __shared__ float ks[HH];
    __shared__ float sraw[CHUNK][NHEAD];
    __shared__ float p[CHUNK][NHEAD];
    __shared__ int   ssrc[CHUNK];
    __shared__ float m[NHEAD], dn[NHEAD], fac[NHEAD];

    ks[t] = k[(size_t)node * HH + t];
    if (t < NHEAD) { m[t] = -3.0e38f; dn[t] = 0.f; }
    const int beg = rowptr[node], end = rowptr[node + 1];
    float acc = 0.f;
    __syncthreads();

    for (int b0 = beg; b0 < end; b0 += CHUNK) {
        const int C = min(CHUNK, end - b0);
        float sc = -3.0e38f;
        if (c < C) {
            int src = csr_src[b0 + c];          // 8 lanes same addr -> broadcast
            if (h == 0) ssrc[c] = src;
            const float* qp = q + (size_t)src * HH + h * HDIM;
            float d0 = 0.f;
            #pragma unroll
            for (int d = 0; d < HDIM; d += 4) {
                float4 qv = *(const float4*)&qp[d];
                d0 += qv.x * ks[h * HDIM + d]     + qv.y * ks[h * HDIM + d + 1]
                    + qv.z * ks[h * HDIM + d + 2] + qv.w * ks[h * HDIM + d + 3];
            }
            sc = d0 * 0.25f + csr_eb[(size_t)(b0 + c) * NHEAD + h];  // contiguous
        }
        sraw[c][h] = sc;
        __syncthreads();
        if (t < NHEAD) {
            float mo = m[t], mc = -3.0e38f;
            #pragma unroll 4
            for (int cc = 0; cc < CHUNK; ++cc) mc = fmaxf(mc, sraw[cc][t]);
            float mn = fmaxf(mo, mc);
            float fa = __expf(mo - mn);
            float s = 0.f;
            #pragma unroll 4
            for (int cc = 0; cc < CHUNK; ++cc) {
                float pe = __expf(sraw[cc][t] - mn);
                p[cc][t] = pe;  s += pe;
            }
            dn[t] = dn[t] * fa + s;
            m[t] = mn;  fac[t] = fa;
        }
        __syncthreads();
        acc *= fac[fh];
        for (int cc = 0; cc < C; ++cc)
            acc += p[cc][fh] * v[(size_t)ssrc[cc] * HH + f];   // 512B coalesced
        __syncthreads();   // protect LDS for next chunk
    }
    agg[(size_t)node * HH + f] = acc / (dn[fh] + 1e-8f);
}

// ---------------------------------------------------------------------------
// K6 (fused tail): out0 = agg@Wo+bo; x1 = LN1(x+out0);
//                  h = gelu(x1@W1+b1); out = LN2(x1 + h@W2+b2)
// ---------------------------------------------------------------------------
__global__ __launch_bounds__(512)
void tail_kernel(const float* __restrict__ x, const float* __restrict__ agg,
                 const float* __restrict__ Wo, const float* __restrict__ bo,
                 const float* __restrict__ l1g, const float* __restrict__ l1b,
                 const float* __restrict__ W1, const float* __restrict__ b1,
                 const float* __restrict__ W2, const float* __restrict__ b2,
                 const float* __restrict__ l2g, const float* __restrict__ l2b,
                 float* __restrict__ out)
{
    const int row0 = blockIdx.x * BM;
    const int t  = threadIdx.x;
    const int rg = t >> 7;
    const int c  = t & 127;
    const int wavehalf = (t >> 6) & 1;

    __shared__ float xs[BM * HH];       // agg tile, then x1 tile
    __shared__ float hs[BM * FFDIM];    // gelu(h) tile
    __shared__ float redS[8][4], redS2[8][4];

    *(float4*)&xs[t * 4] = *(const float4*)&agg[(size_t)row0 * HH + t * 4];
    __syncthreads();

    // ---- oproj ----
    float y[4] = {0.f, 0.f, 0.f, 0.f};
    for (int i0 = 0; i0 < HH; i0 += 4) {
        float4 ar[4];
        #pragma unroll
        for (int r = 0; r < 4; ++r)
            ar[r] = *(const float4*)&xs[(4 * rg + r) * HH + i0];
        #pragma unroll
        for (int u = 0; u < 4; ++u) {
            float w = Wo[(i0 + u) * HH + c];
            #pragma unroll
            for (int r = 0; r < 4; ++r) y[r] += ((const float*)&ar[r])[u] * w;
        }
    }
    {
        float bov = bo[c];
        #pragma unroll
        for (int r = 0; r < 4; ++r)
            y[r] += bov + x[(size_t)(row0 + 4 * rg + r) * HH + c];
    }

    // ---- LN1 ----
    float s[4], s2[4];
    #pragma unroll
    for (int r = 0; r < 4; ++r) { s[r] = y[r]; s2[r] = y[r] * y[r]; }
    #pragma unroll
    for (int off = 32; off > 0; off >>= 1) {
        #pragma unroll
        for (int r = 0; r < 4; ++r) {
            s[r]  += __shfl_down(s[r],  off);
            s2[r] += __shfl_down(s2[r], off);
        }
    }
    if ((t & 63) == 0) {
        #pragma unroll
        for (int r = 0; r < 4; ++r) {
            redS [rg * 2 + wavehalf][r] = s[r];
            redS2[rg * 2 + wavehalf][r] = s2[r];
        }
    }
    __syncthreads();
    float x1v[4];
    {
        float g1 = l1g[c], bb1 = l1b[c];
        #pragma unroll
        for (int r = 0; r < 4; ++r) {
            float ssum = redS [rg * 2][r] + redS [rg * 2 + 1][r];
            float ssq  = redS2[rg * 2][r] + redS2[rg * 2 + 1][r];
            float mean = ssum * (1.0f / HH);
            float var  = ssq  * (1.0f / HH) - mean * mean;
            x1v[r] = (y[r] - mean) * rsqrtf(var + 1e-5f) * g1 + bb1;
        }
    }
    #pragma unroll
    for (int r = 0; r < 4; ++r) xs[(4 * rg + r) * HH + c] = x1v[r];
    __syncthreads();

    // ---- FFN GEMM1 + gelu ----
    float h[4][4];
    #pragma unroll
    for (int r = 0; r < 4; ++r)
        #pragma unroll
        for (int cc = 0; cc < 4; ++cc) h[r][cc] = 0.f;
    for (int i0 = 0; i0 < HH; i0 += 4) {
        float4 xr[4];
        #pragma unroll
        for (int r = 0; r < 4; ++r)
            xr[r] = *(const float4*)&xs[(4 * rg + r) * HH + i0];
        #pragma unroll
        for (int u = 0; u < 4; ++u) {
            float4 w = *(const float4*)&W1[(size_t)(i0 + u) * FFDIM + 4 * c];
            #pragma unroll
            for (int r = 0; r < 4; ++r) {
                float xv = ((const float*)&xr[r])[u];
                h[r][0] += xv * w.x;  h[r][1] += xv * w.y;
                h[r][2] += xv * w.z;  h[r][3] += xv * w.w;
            }
        }
    }
    {
        float4 b1v = *(const float4*)&b1[4 * c];
        #pragma unroll
        for (int r = 0; r < 4; ++r) {
            float4 hv;
            float a0 = h[r][0] + b1v.x, a1 = h[r][1] + b1v.y;
            float a2 = h[r][2] + b1v.z, a3 = h[r][3] + b1v.w;
            hv.x = 0.5f * a0 * (1.0f + erff(a0 * 0.70710678118f));
            hv.y = 0.5f * a1 * (1.0f + erff(a1 * 0.70710678118f));
            hv.z = 0.5f * a2 * (1.0f + erff(a2 * 0.70710678118f));
            hv.w = 0.5f * a3 * (1.0f + erff(a3 * 0.70710678118f));
            *(float4*)&hs[(4 * rg + r) * FFDIM + 4 * c] = hv;
        }
    }
    __syncthreads();

    // ---- FFN GEMM2 ----
    float y2[4] = {0.f, 0.f, 0.f, 0.f};
    for (int j0 = 0; j0 < FFDIM; j0 += 4) {
        float4 hr[4];
        #pragma unroll
        for (int r = 0; r < 4; ++r)
            hr[r] = *(const float4*)&hs[(4 * rg + r) * FFDIM + j0];
        #pragma unroll
        for (int u = 0; u < 4; ++u) {
            float w = W2[(size_t)(j0 + u) * HH + c];
            #pragma unroll
            for (int r = 0; r < 4; ++r) y2[r] += ((const float*)&hr[r])[u] * w;
        }
    }
    {
        float b2v = b2[c];
        #pragma unroll
        for (int r = 0; r < 4; ++r) y2[r] += b2v + x1v[r];
    }

    // ---- LN2 ----
    #pragma unroll
    for (int r = 0; r < 4; ++r) { s[r] = y2[r]; s2[r] = y2[r] * y2[r]; }
    #pragma unroll
    for (int off = 32; off > 0; off >>= 1) {
        #pragma unroll
        for (int r = 0; r < 4; ++r) {
            s[r]  += __shfl_down(s[r],  off);
            s2[r] += __shfl_down(s2[r], off);
        }
    }
    if ((t & 63) == 0) {
        #pragma unroll
        for (int r = 0; r < 4; ++r) {
            redS [rg * 2 + wavehalf][r] = s[r];
            redS2[rg * 2 + wavehalf][r] = s2[r];
        }
    }
    __syncthreads();
    {
        float g2 = l2g[c], bb2 = l2b[c];
        #pragma unroll
        for (int r = 0; r < 4; ++r) {
            float ssum = redS [rg * 2][r] + redS [rg * 2 + 1][r];
            float ssq  = redS2[rg * 2][r] + redS2[rg * 2 + 1][r];
            float mean = ssum * (1.0f / HH);
            float var  = ssq  * (1.0f / HH) - mean * mean;
            out[(size_t)(row0 + 4 * rg + r) * HH + c] =
                (y2[r] - mean) * rsqrtf(var + 1e-5f) * g2 + bb2;
        }
    }
}

// ---------------------------------------------------------------------------
extern "C" void kernel_launch(void* const* d_in, const int* in_sizes, int n_in,
                              void* d_out, int out_size, void* d_ws, size_t ws_size,
                              hipStream_t stream)
{
    const float* x   = (const float*)d_in[0];
    const int*   ei  = (const int*)d_in[1];
    const float* ea  = (const float*)d_in[2];
    const float* Wq  = (const float*)d_in[3];
    const float* bq  = (const float*)d_in[4];
    const float* Wk  = (const float*)d_in[5];
    const float* bk  = (const float*)d_in[6];
    const float* Wv  = (const float*)d_in[7];
    const float* bv  = (const float*)d_in[8];
    const float* We  = (const float*)d_in[9];
    const float* be  = (const float*)d_in[10];
    const float* Wo  = (const float*)d_in[11];
    const float* bo  = (const float*)d_in[12];
    const float* l1g = (const float*)d_in[13];
    const float* l1b = (const float*)d_in[14];
    const float* W1  = (const float*)d_in[15];
    const float* b1  = (const float*)d_in[16];
    const float* W2  = (const float*)d_in[17];
    const float* b2  = (const float*)d_in[18];
    const float* l2g = (const float*)d_in[19];
    const float* l2b = (const float*)d_in[20];
    float* out = (float*)d_out;

    const int n = in_sizes[0] / HH;       // 10000
    const int E = in_sizes[1] / 2;        // 320000

    float* ws      = (float*)d_ws;
    float* q       = ws;
    float* k       = q       + (size_t)n * HH;
    float* v       = k       + (size_t)n * HH;
    float* csr_eb  = v       + (size_t)n * HH;            // E*8 floats
    float* agg     = csr_eb  + (size_t)E * NHEAD;         // n*128 floats
    int*   cnt     = (int*)(agg + (size_t)n * HH);        // n ints
    int*   cursor  = cnt     + n;                         // n ints
    int*   rowptr  = cursor  + n;                         // n+1 ints
    int*   csr_src = rowptr  + (n + 1);                   // E ints

    qkv_kernel<<<n / BM, 512, 0, stream>>>(x, Wq, bq, Wk, bk, Wv, bv,
                                           q, k, v, cnt, cursor);
    hist_kernel<<<(E + 255) / 256, 256, 0, stream>>>(ei, E, cnt);
    scan_kernel<<<1, SCAN_T, 0, stream>>>(cnt, n, rowptr);
    scatter_kernel<<<(E + 255) / 256, 256, 0, stream>>>(ei, E, ea, We, be,
                                                        rowptr, cursor,
                                                        csr_src, csr_eb);
    edge_kernel<<<n, 128, 0, stream>>>(q, k, v, rowptr, csr_src, csr_eb, agg);
    tail_kernel<<<n / BM, 512, 0, stream>>>(x, agg, Wo, bo, l1g, l1b,
                                            W1, b1, W2, b2, l2g, l2b, out);
}